// Round 4
// baseline (243.489 us; speedup 1.0000x reference)
//
#include <hip/hip_runtime.h>
#include <hip/hip_bf16.h>
#include <math.h>

#define Bb 8
#define Hh 512
#define N2 32
#define Ll 4096
#define CH 256
#define NCH 16

// scratch in d_out (floats); y_bf16 occupies d_out bytes [0, 32MiB)
#define KG_OFF  8388608
#define CKR_OFF (KG_OFF + 131072)
#define CKI_OFF (CKR_OFF + 16384)
#define W256R_OFF (CKI_OFF + 16384)
#define W256I_OFF (W256R_OFF + 16384)
// per-h bf16 tables, ushort indices into d_out:
//   WNHI: 512 * 64*264 at byte 36MiB; WNLO: 512 * 64*136 at byte 52.5MiB
#define WNHI_OFF 18874368u
#define WNLO_OFF 27525120u

typedef short bf16x8 __attribute__((ext_vector_type(8)));
typedef float f32x4  __attribute__((ext_vector_type(4)));

__device__ __forceinline__ float gelu_f(float x) {
    return 0.5f * x * (1.f + erff(x * 0.70710678118654752f));
}
__device__ __forceinline__ unsigned short f2bf(float f) {
    __hip_bfloat16 h = __float2bfloat16(f);
    return *reinterpret_cast<unsigned short*>(&h);
}
__device__ __forceinline__ float bf2f(unsigned short s) {
    return __uint_as_float(((unsigned int)s) << 16);
}
__device__ __forceinline__ void gl2lds16(const void* g, void* l) {
    __builtin_amdgcn_global_load_lds(
        (const __attribute__((address_space(1))) void*)g,
        (__attribute__((address_space(3))) void*)l, 16, 0, 0);
}

// ---------- K1: per h, k[h,0..255], 2*Ck[h,n], w256, Wn tables; W -> bf16 ----
__global__ __launch_bounds__(256) void s4d_k1(
    const float* __restrict__ log_dt,
    const float* __restrict__ C_re,  const float* __restrict__ C_im,
    const float* __restrict__ log_A_real, const float* __restrict__ A_imag,
    const float* __restrict__ W,
    float* __restrict__ scratch, unsigned short* __restrict__ Wb,
    unsigned short* __restrict__ wnhi, unsigned short* __restrict__ wnlo,
    unsigned short* __restrict__ wnt)
{
    __shared__ __align__(16) float wLr[N2][257];
    __shared__ __align__(16) float wLi[N2][257];
    __shared__ float Ck2r[N2], Ck2i[N2];

    const int tid = threadIdx.x;
    const int h = blockIdx.x;

    // W fp32 -> bf16 (flat)
    {
        const int i4 = (blockIdx.x * 256 + tid) * 4;
        const float4 wv = *(const float4*)&W[i4];
        unsigned short o[4] = {f2bf(wv.x), f2bf(wv.y), f2bf(wv.z), f2bf(wv.w)};
        *(uint2*)&Wb[i4] = *(uint2*)o;
    }

    const float dt = expf(log_dt[h]);
    const int n = tid & 31, tq = tid >> 5;

    const float lar = log_A_real[h * N2 + n];
    const float Aim = A_imag[h * N2 + n];
    const float Are = -expf(lar);
    const float dar = Are * dt, dai = Aim * dt;

    float wr, wi;
    { float e = expf(dar); float sn, cs; sincosf(dai, &sn, &cs); wr = e * cs; wi = e * sn; }
    const float j0 = (float)(32 * tq + 1);
    float cr, ci;
    { float e = expf(dar * j0); float sn, cs; sincosf(dai * j0, &sn, &cs); cr = e * cs; ci = e * sn; }
    #pragma unroll 8
    for (int i = 0; i < 32; ++i) {
        const int j = 32 * tq + i;
        wLr[n][j] = cr; wLi[n][j] = ci;   // wL[n][j] == w^(j+1)
        const float tr = cr * wr - ci * wi;
        ci = cr * wi + ci * wr; cr = tr;
    }

    if (tid < N2) {
        const float er = wr - 1.f, ei = wi;
        const float den = Are * Are + Aim * Aim;
        const float qr = (er * Are + ei * Aim) / den;
        const float qi = (ei * Are - er * Aim) / den;
        const float c_r = C_re[h * N2 + tid], c_i = C_im[h * N2 + tid];
        const float k2r = 2.f * (c_r * qr - c_i * qi);
        const float k2i = 2.f * (c_r * qi + c_i * qr);
        Ck2r[tid] = k2r; Ck2i[tid] = k2i;
        scratch[CKR_OFF + h * 32 + tid] = k2r;
        scratch[CKI_OFF + h * 32 + tid] = k2i;
    }
    __syncthreads();

    {
        const int t = tid;
        float kv = 0.f;
        if (t == 0) {
            #pragma unroll
            for (int m = 0; m < N2; ++m) kv += Ck2r[m];
        } else {
            #pragma unroll
            for (int m = 0; m < N2; ++m)
                kv += Ck2r[m] * wLr[m][t - 1] - Ck2i[m] * wLi[m][t - 1];
        }
        scratch[KG_OFF + h * CH + t] = kv;
    }

    // ---- per-h tables consumed by k23 (all pure reads of wLr/wLi) ----------
    {
        unsigned short* WH  = wnhi + (size_t)h * (64 * 264);
        unsigned short* WLo = wnlo + (size_t)h * (64 * 136);
        unsigned short* WT  = wnt  + (size_t)h * (257 * 64);

        // WNHI[r][j] = bf16(w^j), rows r: 2n=Re, 2n+1=Im; cols 0..256 valid
        for (int idx = tid; idx < 64 * 33; idx += 256) {
            const int r = idx / 33, g = idx - 33 * r;
            const float* src = (r & 1) ? wLi[r >> 1] : wLr[r >> 1];
            __align__(16) unsigned short o[8];
            #pragma unroll
            for (int jj = 0; jj < 8; ++jj) {
                const int j = 8 * g + jj;
                const float v = (j == 0) ? ((r & 1) ? 0.f : 1.f)
                              : (j <= 256 ? src[j - 1] : 0.f);
                o[jj] = f2bf(v);
            }
            *(uint4*)&WH[r * 264 + 8 * g] = *(const uint4*)o;
        }
        // WNLO[r][j] = bf16(w^j - bf16(w^j)), j<128 (else 0)
        for (int idx = tid; idx < 64 * 17; idx += 256) {
            const int r = idx / 17, g = idx - 17 * r;
            const float* src = (r & 1) ? wLi[r >> 1] : wLr[r >> 1];
            __align__(16) unsigned short o[8];
            #pragma unroll
            for (int jj = 0; jj < 8; ++jj) {
                const int j = 8 * g + jj;
                const float v = (j == 0) ? ((r & 1) ? 0.f : 1.f)
                              : (j < 128 ? src[j - 1] : 0.f);
                o[jj] = f2bf(v - bf2f(f2bf(v)));
            }
            *(uint4*)&WLo[r * 136 + 8 * g] = *(const uint4*)o;
        }
        // WNT[t][r] = bf16(w^t) transposed, t in [0,257)
        for (int idx = tid; idx < 257 * 8; idx += 256) {
            const int t = idx >> 3, g = idx & 7;
            __align__(16) unsigned short o[8];
            #pragma unroll
            for (int rr = 0; rr < 8; ++rr) {
                const int r = 8 * g + rr;
                const float v = (t == 0) ? ((r & 1) ? 0.f : 1.f)
                              : ((r & 1) ? wLi[r >> 1][t - 1] : wLr[r >> 1][t - 1]);
                o[rr] = f2bf(v);
            }
            *(uint4*)&WT[t * 64 + 8 * g] = *(const uint4*)o;
        }
        if (tid < N2) {
            scratch[W256R_OFF + h * 32 + tid] = wLr[tid][255];   // w^256
            scratch[W256I_OFF + h * 32 + tid] = wLi[tid][255];
        }
    }
}

// ---------- K23: MFMA-ized Toeplitz + P + scan + state + GELU ----------------
// blockIdx remapped so the 8 batch-blocks of one h are adjacent in dispatch
// order AND congruent mod 8 (same XCD) -> per-h tables stay L2-hot.
__global__ __launch_bounds__(256, 3) void s4d_k23(
    const float* __restrict__ u,
    const float* __restrict__ Dp,
    const float* scratch,
    const unsigned short* wnhi, const unsigned short* wnlo,
    const unsigned short* wnt,
    unsigned short* y_bf)
{
    __shared__ __align__(16) unsigned short uhi[16 * 264];   // u reversed, bf16 hi
    __shared__ __align__(16) unsigned short ulo[16 * 264];   // residual
    __shared__ __align__(16) unsigned short khi[8 * 520];    // karr2 shifted copies
    __shared__ __align__(16) unsigned short klo[8 * 520];
    __shared__ __align__(16) float Plds[64 * 17];
    __shared__ __align__(16) unsigned short CkAhi[16 * 72];  // [c][2n] CkS split
    __shared__ __align__(16) unsigned short CkAlo[16 * 72];

    const int tid = threadIdx.x;
    // bijective remap: x = (h>>3)<<6 | b<<3 | (h&7)
    const int x = blockIdx.x;
    const int h = ((x >> 6) << 3) | (x & 7);
    const int b = (x >> 3) & 7;
    const int wv = tid >> 6;
    const int lane = tid & 63;
    const int l15 = lane & 15;
    const int quad = lane >> 4;

    // scan inputs hoisted to kernel top: global latency hides under A1/A2
    const int nsc = tid & 31;
    const float sc_k2r = scratch[CKR_OFF + h * 32 + nsc];
    const float sc_k2i = scratch[CKI_OFF + h * 32 + nsc];
    const float sc_wCr = scratch[W256R_OFF + h * 32 + nsc];
    const float sc_wCi = scratch[W256I_OFF + h * 32 + nsc];

    // ---- phase A1: zero karr, u->reversed splits ----
    {
        unsigned int* z1 = (unsigned int*)khi;
        unsigned int* z2 = (unsigned int*)klo;
        for (int i = tid; i < 2080; i += 256) { z1[i] = 0; z2[i] = 0; }
    }
    const float* ub = u + (size_t)(b * Hh + h) * Ll;
    #pragma unroll
    for (int q = 0; q < 4; ++q) {
        const int l = q * 1024 + tid * 4;
        const float4 v = *(const float4*)&ub[l];
        const int c = l >> 8, s = l & 255;
        const unsigned short h3 = f2bf(v.w), h2 = f2bf(v.z), h1 = f2bf(v.y), h0 = f2bf(v.x);
        // u_rev[c][252-s .. 255-s] = (u[s+3], u[s+2], u[s+1], u[s])
        uint2 dh;
        dh.x = (unsigned int)h3 | ((unsigned int)h2 << 16);
        dh.y = (unsigned int)h1 | ((unsigned int)h0 << 16);
        *(uint2*)&uhi[c * 264 + (252 - s)] = dh;
        uint2 dl;
        dl.x = (unsigned int)f2bf(v.w - bf2f(h3)) | ((unsigned int)f2bf(v.z - bf2f(h2)) << 16);
        dl.y = (unsigned int)f2bf(v.y - bf2f(h1)) | ((unsigned int)f2bf(v.x - bf2f(h0)) << 16);
        *(uint2*)&ulo[c * 264 + (252 - s)] = dl;
    }
    // own k value for later scatter
    const float kval = scratch[KG_OFF + h * CH + tid];
    const unsigned short k_hi = f2bf(kval);
    const unsigned short k_lo = f2bf(kval - bf2f(k_hi));
    __syncthreads();

    // ---- phase A2: scatter k into 8 shifted copies; P-matmul (3-product) ----
    #pragma unroll
    for (int r = 0; r < 8; ++r) {
        const int x2 = tid + 255 - r;
        khi[r * 520 + x2] = k_hi;
        klo[r * 520 + x2] = k_lo;
    }
    {   // P^T[c][2n]: wave wv owns 2n-cols [16wv, 16wv+16)
        const unsigned short* WH = wnhi + (size_t)h * (64 * 264);
        const unsigned short* WL = wnlo + (size_t)h * (64 * 136);
        f32x4 accP = {0.f, 0.f, 0.f, 0.f};
        const int wrow = 16 * wv + l15;
        #pragma unroll
        for (int j0 = 0; j0 < 256; j0 += 32) {
            const bf16x8 ah = *(const bf16x8*)&uhi[l15 * 264 + j0 + 8 * quad];
            const bf16x8 al = *(const bf16x8*)&ulo[l15 * 264 + j0 + 8 * quad];
            const bf16x8 wh = *(const bf16x8*)&WH[wrow * 264 + j0 + 8 * quad];
            accP = __builtin_amdgcn_mfma_f32_16x16x32_bf16(ah, wh, accP, 0, 0, 0);
            accP = __builtin_amdgcn_mfma_f32_16x16x32_bf16(al, wh, accP, 0, 0, 0);
            if (j0 < 128) {   // w-lo correction, same 3-product scheme as Toeplitz
                const bf16x8 wl = *(const bf16x8*)&WL[wrow * 136 + j0 + 8 * quad];
                accP = __builtin_amdgcn_mfma_f32_16x16x32_bf16(ah, wl, accP, 0, 0, 0);
            }
        }
        const int pbase = wrow * 17 + 4 * quad;
        Plds[pbase + 0] = accP[0];
        Plds[pbase + 1] = accP[1];
        Plds[pbase + 2] = accP[2];
        Plds[pbase + 3] = accP[3];
    }
    __syncthreads();

    // ---- pre-issue state-matmul B-frags from WnT (consumed after Toeplitz) ----
    bf16x8 sf[8];
    {
        const unsigned short* WT = wnt + (size_t)h * (257 * 64);
        #pragma unroll
        for (int ks2 = 0; ks2 < 2; ++ks2)
            #pragma unroll
            for (int i = 0; i < 4; ++i) {
                const int tcol = 16 * (wv + 4 * i) + l15 + 1;
                sf[ks2 * 4 + i] = *(const bf16x8*)&WT[tcol * 64 + 32 * ks2 + 8 * quad];
            }
    }

    // ---- scan (wave0 lanes 0..31) runs concurrent with Toeplitz ----
    if (tid < 32) {
        const int n = tid;
        const float k2r = sc_k2r, k2i = sc_k2i;
        const float wCr = sc_wCr, wCi = sc_wCi;
        float sr = 0.f, si = 0.f;
        #pragma unroll
        for (int c = 0; c < NCH; ++c) {
            const float vr = k2r * sr - k2i * si;       // A[c][2n]   =  Re(CkS)
            const float vi = -(k2r * si + k2i * sr);    // A[c][2n+1] = -Im(CkS)
            const unsigned short vrh = f2bf(vr), vih = f2bf(vi);
            *(unsigned int*)&CkAhi[c * 72 + 2 * n] =
                (unsigned int)vrh | ((unsigned int)vih << 16);
            *(unsigned int*)&CkAlo[c * 72 + 2 * n] =
                (unsigned int)f2bf(vr - bf2f(vrh)) |
                ((unsigned int)f2bf(vi - bf2f(vih)) << 16);
            const float pr = Plds[(2 * n) * 17 + c], pi = Plds[(2 * n + 1) * 17 + c];
            const float nr = wCr * sr - wCi * si + pr;
            si = wCr * si + wCi * sr + pi;
            sr = nr;
        }
    }

    // ---- Toeplitz: y^T[c][t] += sum_j u_rev[c][j] * karr2[t+j] ----
    f32x4 acc[4];
    #pragma unroll
    for (int i = 0; i < 4; ++i) acc[i] = (f32x4){0.f, 0.f, 0.f, 0.f};
    {
        const int r = lane & 7;
        const int roff = r * 520;
        const int half = ((lane >> 3) & 1) * 8;
        #pragma unroll
        for (int i = 0; i < 4; ++i) {
            const int nt = wv + 4 * i;
            const int jstart = (240 - 16 * nt) & ~31;
            for (int j0 = jstart; j0 < 256; j0 += 32) {
                const bf16x8 ah = *(const bf16x8*)&uhi[l15 * 264 + j0 + 8 * quad];
                const bf16x8 al = *(const bf16x8*)&ulo[l15 * 264 + j0 + 8 * quad];
                const int base = 16 * nt + j0 + 8 * quad + half;
                const bf16x8 bh = *(const bf16x8*)&khi[roff + base];
                const bf16x8 bl = *(const bf16x8*)&klo[roff + base];
                acc[i] = __builtin_amdgcn_mfma_f32_16x16x32_bf16(ah, bh, acc[i], 0, 0, 0);
                acc[i] = __builtin_amdgcn_mfma_f32_16x16x32_bf16(ah, bl, acc[i], 0, 0, 0);
                acc[i] = __builtin_amdgcn_mfma_f32_16x16x32_bf16(al, bh, acc[i], 0, 0, 0);
            }
        }
    }
    __syncthreads();

    // ---- state matmul: acc[c][t] += sum_{2n} CkA[c][2n] * Wn[2n][t+1] ----
    #pragma unroll
    for (int ks2 = 0; ks2 < 2; ++ks2) {
        const int ks = 32 * ks2;
        const bf16x8 ah = *(const bf16x8*)&CkAhi[l15 * 72 + ks + 8 * quad];
        const bf16x8 al = *(const bf16x8*)&CkAlo[l15 * 72 + ks + 8 * quad];
        #pragma unroll
        for (int i = 0; i < 4; ++i) {
            acc[i] = __builtin_amdgcn_mfma_f32_16x16x32_bf16(ah, sf[ks2 * 4 + i], acc[i], 0, 0, 0);
            acc[i] = __builtin_amdgcn_mfma_f32_16x16x32_bf16(al, sf[ks2 * 4 + i], acc[i], 0, 0, 0);
        }
    }

    // ---- epilogue: +D*u, GELU, bf16 store ----
    const float Dh = Dp[h];
    unsigned short* yo = y_bf + (size_t)(b * Hh + h) * Ll;
    #pragma unroll
    for (int i = 0; i < 4; ++i) {
        const int t = 16 * (wv + 4 * i) + l15;
        const int jrev = 255 - t;
        #pragma unroll
        for (int rr = 0; rr < 4; ++rr) {
            const int c = 4 * quad + rr;
            const float uu = bf2f(uhi[c * 264 + jrev]) + bf2f(ulo[c * 264 + jrev]);
            const float yv = acc[i][rr] + Dh * uu;
            yo[c * 256 + t] = f2bf(gelu_f(yv));
        }
    }
}

// ---------- T: y_bf (b,k,l) -> y_T (b,l,k), swizzled LDS transpose -----------
__global__ __launch_bounds__(256) void s4d_T(
    const unsigned short* y_bf, unsigned short* __restrict__ y_T)
{
    __shared__ unsigned short T[64][72];
    const int tid = threadIdx.x;
    const int b  = blockIdx.x >> 9;
    const int k0 = ((blockIdx.x >> 6) & 7) << 6;
    const int l0 = (blockIdx.x & 63) << 6;

    #pragma unroll
    for (int q = 0; q < 2; ++q) {
        const int idx = tid + 256 * q;
        const int kk = idx >> 3, lg = idx & 7;
        const uint4 v = *(const uint4*)&y_bf[((size_t)(b * Hh + k0 + kk)) * Ll + l0 + 8 * lg];
        const int gp = lg ^ ((kk >> 3) & 7);
        *(uint4*)&T[kk][8 * gp] = v;
    }
    __syncthreads();
    #pragma unroll
    for (int q = 0; q < 2; ++q) {
        const int idx = tid + 256 * q;
        const int ll = idx >> 3, kg = idx & 7;
        unsigned short o[8];
        #pragma unroll
        for (int j = 0; j < 8; ++j) {
            const int kr = 8 * kg + j;
            const int gp = (ll >> 3) ^ kg;
            o[j] = T[kr][8 * gp + (ll & 7)];
        }
        *(uint4*)&y_T[((size_t)(b * Ll + l0 + ll)) * Hh + k0 + 8 * kg] = *(uint4*)o;
    }
}

// ---------- Stage 2: 128x128 MFMA GEMM + GLU --------------------------------
// 1-D grid remapped so the 8 mt-blocks sharing a Y panel are adjacent in
// dispatch order AND congruent mod 8 (same XCD) -> Y re-reads are L2 hits.
// W (A-operand) read directly from global (1 MB, L2-hot); only Y staged in
// LDS via global_load_lds + source-XOR swizzle. launch_bounds(256,4): the
// 64-VGPR accumulator footprint makes 4 blocks/CU the real occupancy cap.
__global__ __launch_bounds__(256, 4) void s4d_s2(
    const unsigned short* __restrict__ yT,
    const unsigned short* __restrict__ Wb,
    const float* __restrict__ bias,
    float* __restrict__ out)
{
    __shared__ __align__(16) unsigned short Ylds[128 * 64];  // rows = l

    const int tid = threadIdx.x;
    const int x  = blockIdx.x;                 // 0..2047
    const int ctg = ((x >> 6) << 3) | (x & 7); // 0..255
    const int mt  = (x >> 3) & 7;              // 0..7
    const int b  = ctg >> 5;
    const int l0 = (ctg & 31) << 7;
    const int m0 = mt << 6;

    const int wv = tid >> 6, lane = tid & 63;
    const int l15 = lane & 15, quad = lane >> 4;

    f32x4 accA[8], accG[8];
    #pragma unroll
    for (int j = 0; j < 8; ++j) {
        accA[j] = (f32x4){0.f, 0.f, 0.f, 0.f};
        accG[j] = (f32x4){0.f, 0.f, 0.f, 0.f};
    }

    const unsigned short* Wa = Wb + (size_t)(m0 + 16 * wv + l15) * Hh;
    const unsigned short* Wg = Wb + (size_t)(512 + m0 + 16 * wv + l15) * Hh;

    for (int kk = 0; kk < Hh; kk += 64) {
        #pragma unroll
        for (int q = 0; q < 4; ++q) {
            const int idx = tid + 256 * q;
            const int rr = idx >> 3, kg = idx & 7;
            const int sw = kg ^ (rr & 7);              // source chunk permutation
            gl2lds16(&yT[((size_t)(b * Ll + l0 + rr)) * Hh + kk + 8 * sw], &Ylds[8 * idx]);
        }
        __syncthreads();

        #pragma unroll
        for (int ks = 0; ks < 64; ks += 32) {
            const int c0 = (ks >> 3) + quad;
            const bf16x8 af = *(const bf16x8*)&Wa[kk + 8 * c0];
            const bf16x8 gf = *(const bf16x8*)&Wg[kk + 8 * c0];
            #pragma unroll
            for (int j = 0; j < 8; ++j) {
                const int brow = 16 * j + l15;
                const bf16x8 bfr = *(const bf16x8*)&Ylds[brow * 64 + 8 * (c0 ^ (brow & 7))];
                accA[j] = __builtin_amdgcn_mfma_f32_16x16x32_bf16(af, bfr, accA[j], 0, 0, 0);
                accG[j] = __builtin_amdgcn_mfma_f32_16x16x32_bf16(gf, bfr, accG[j], 0, 0, 0);
            }
        }
        __syncthreads();
    }

    const int mb = m0 + 16 * wv + 4 * quad;
    float bA[4], bG[4];
    #pragma unroll
    for (int rr = 0; rr < 4; ++rr) { bA[rr] = bias[mb + rr]; bG[rr] = bias[mb + rr + 512]; }

    #pragma unroll
    for (int j = 0; j < 8; ++j) {
        const int l = l0 + 16 * j + l15;
        #pragma unroll
        for (int rr = 0; rr < 4; ++rr) {
            const float a = accA[j][rr] + bA[rr];
            const float g = accG[j][rr] + bG[rr];
            out[((size_t)(b * Hh + mb + rr)) * Ll + l] = a / (1.f + expf(-g));
        }
    }
}

extern "C" void kernel_launch(void* const* d_in, const int* in_sizes, int n_in,
                              void* d_out, int out_size, void* d_ws, size_t ws_size,
                              hipStream_t stream)
{
    const float* u          = (const float*)d_in[0];
    const float* log_dt     = (const float*)d_in[1];
    const float* C_re       = (const float*)d_in[2];
    const float* C_im       = (const float*)d_in[3];
    const float* log_A_real = (const float*)d_in[4];
    const float* A_imag     = (const float*)d_in[5];
    const float* Dp         = (const float*)d_in[6];
    const float* W          = (const float*)d_in[7];
    const float* bias       = (const float*)d_in[8];

    float* out = (float*)d_out;
    float* scratch = (float*)d_out;                         // floats [32Mi, ...)
    unsigned short* y_bf = (unsigned short*)d_out;          // bf16 [0, 32MiB)
    unsigned short* wnhi = (unsigned short*)d_out + WNHI_OFF;  // 16.5 MiB @ 36 MiB
    unsigned short* wnlo = (unsigned short*)d_out + WNLO_OFF;  // 8.5 MiB @ 52.5 MiB
    unsigned short* y_T  = (unsigned short*)d_ws;           // 32 MiB
    unsigned short* wnt  = (unsigned short*)d_ws;           // 16.1 MiB, freed before s4d_T writes y_T
    unsigned short* Wb   = (unsigned short*)((char*)d_ws + (32u << 20)); // 1 MiB

    s4d_k1<<<dim3(Hh), dim3(256), 0, stream>>>(
        log_dt, C_re, C_im, log_A_real, A_imag, W, scratch, Wb, wnhi, wnlo, wnt);
    s4d_k23<<<dim3(Bb * Hh), dim3(256), 0, stream>>>(
        u, Dp, scratch, wnhi, wnlo, wnt, y_bf);
    s4d_T<<<dim3(Bb * Hh), dim3(256), 0, stream>>>(y_bf, y_T);
    s4d_s2<<<dim3(2048), dim3(256), 0, stream>>>(y_T, Wb, bias, out);
}

// Round 5
// 233.178 us; speedup vs baseline: 1.0442x; 1.0442x over previous
//
#include <hip/hip_runtime.h>
#include <hip/hip_bf16.h>
#include <math.h>

#define Bb 8
#define Hh 512
#define N2 32
#define Ll 4096
#define CH 256
#define NCH 16

// scratch in d_out (floats); y_bf16 occupies d_out bytes [0, 32MiB)
#define KG_OFF  8388608
#define CKR_OFF (KG_OFF + 131072)
#define CKI_OFF (CKR_OFF + 16384)
#define W256R_OFF (CKI_OFF + 16384)
#define W256I_OFF (W256R_OFF + 16384)
// per-h bf16 tables, ushort indices into d_out:
//   WNHI: 512 * 64*264 at byte 36MiB; WNLO: 512 * 64*136 at byte 52.5MiB
#define WNHI_OFF 18874368u
#define WNLO_OFF 27525120u

typedef short bf16x8 __attribute__((ext_vector_type(8)));
typedef float f32x4  __attribute__((ext_vector_type(4)));

__device__ __forceinline__ float gelu_f(float x) {
    return 0.5f * x * (1.f + erff(x * 0.70710678118654752f));
}
__device__ __forceinline__ unsigned short f2bf(float f) {
    __hip_bfloat16 h = __float2bfloat16(f);
    return *reinterpret_cast<unsigned short*>(&h);
}
__device__ __forceinline__ float bf2f(unsigned short s) {
    return __uint_as_float(((unsigned int)s) << 16);
}
__device__ __forceinline__ void gl2lds16(const void* g, void* l) {
    __builtin_amdgcn_global_load_lds(
        (const __attribute__((address_space(1))) void*)g,
        (__attribute__((address_space(3))) void*)l, 16, 0, 0);
}

// ---------- K1: per h, k[h,0..255], 2*Ck[h,n], w256, Wn tables; W -> bf16 ----
__global__ __launch_bounds__(256) void s4d_k1(
    const float* __restrict__ log_dt,
    const float* __restrict__ C_re,  const float* __restrict__ C_im,
    const float* __restrict__ log_A_real, const float* __restrict__ A_imag,
    const float* __restrict__ W,
    float* __restrict__ scratch, unsigned short* __restrict__ Wb,
    unsigned short* __restrict__ wnhi, unsigned short* __restrict__ wnlo,
    unsigned short* __restrict__ wnt)
{
    __shared__ __align__(16) float wLr[N2][257];
    __shared__ __align__(16) float wLi[N2][257];
    __shared__ float Ck2r[N2], Ck2i[N2];

    const int tid = threadIdx.x;
    const int h = blockIdx.x;

    // W fp32 -> bf16 (flat)
    {
        const int i4 = (blockIdx.x * 256 + tid) * 4;
        const float4 wv = *(const float4*)&W[i4];
        unsigned short o[4] = {f2bf(wv.x), f2bf(wv.y), f2bf(wv.z), f2bf(wv.w)};
        *(uint2*)&Wb[i4] = *(uint2*)o;
    }

    const float dt = expf(log_dt[h]);
    const int n = tid & 31, tq = tid >> 5;

    const float lar = log_A_real[h * N2 + n];
    const float Aim = A_imag[h * N2 + n];
    const float Are = -expf(lar);
    const float dar = Are * dt, dai = Aim * dt;

    float wr, wi;
    { float e = expf(dar); float sn, cs; sincosf(dai, &sn, &cs); wr = e * cs; wi = e * sn; }
    const float j0 = (float)(32 * tq + 1);
    float cr, ci;
    { float e = expf(dar * j0); float sn, cs; sincosf(dai * j0, &sn, &cs); cr = e * cs; ci = e * sn; }
    #pragma unroll 8
    for (int i = 0; i < 32; ++i) {
        const int j = 32 * tq + i;
        wLr[n][j] = cr; wLi[n][j] = ci;   // wL[n][j] == w^(j+1)
        const float tr = cr * wr - ci * wi;
        ci = cr * wi + ci * wr; cr = tr;
    }

    if (tid < N2) {
        const float er = wr - 1.f, ei = wi;
        const float den = Are * Are + Aim * Aim;
        const float qr = (er * Are + ei * Aim) / den;
        const float qi = (ei * Are - er * Aim) / den;
        const float c_r = C_re[h * N2 + tid], c_i = C_im[h * N2 + tid];
        const float k2r = 2.f * (c_r * qr - c_i * qi);
        const float k2i = 2.f * (c_r * qi + c_i * qr);
        Ck2r[tid] = k2r; Ck2i[tid] = k2i;
        scratch[CKR_OFF + h * 32 + tid] = k2r;
        scratch[CKI_OFF + h * 32 + tid] = k2i;
    }
    __syncthreads();

    {
        const int t = tid;
        float kv = 0.f;
        if (t == 0) {
            #pragma unroll
            for (int m = 0; m < N2; ++m) kv += Ck2r[m];
        } else {
            #pragma unroll
            for (int m = 0; m < N2; ++m)
                kv += Ck2r[m] * wLr[m][t - 1] - Ck2i[m] * wLi[m][t - 1];
        }
        scratch[KG_OFF + h * CH + t] = kv;
    }

    // ---- per-h tables consumed by k23 (all pure reads of wLr/wLi) ----------
    {
        unsigned short* WH  = wnhi + (size_t)h * (64 * 264);
        unsigned short* WLo = wnlo + (size_t)h * (64 * 136);
        unsigned short* WT  = wnt  + (size_t)h * (257 * 64);

        // WNHI[r][j] = bf16(w^j), rows r: 2n=Re, 2n+1=Im; cols 0..256 valid
        for (int idx = tid; idx < 64 * 33; idx += 256) {
            const int r = idx / 33, g = idx - 33 * r;
            const float* src = (r & 1) ? wLi[r >> 1] : wLr[r >> 1];
            __align__(16) unsigned short o[8];
            #pragma unroll
            for (int jj = 0; jj < 8; ++jj) {
                const int j = 8 * g + jj;
                const float v = (j == 0) ? ((r & 1) ? 0.f : 1.f)
                              : (j <= 256 ? src[j - 1] : 0.f);
                o[jj] = f2bf(v);
            }
            *(uint4*)&WH[r * 264 + 8 * g] = *(const uint4*)o;
        }
        // WNLO[r][j] = bf16(w^j - bf16(w^j)), j<128 (else 0)
        for (int idx = tid; idx < 64 * 17; idx += 256) {
            const int r = idx / 17, g = idx - 17 * r;
            const float* src = (r & 1) ? wLi[r >> 1] : wLr[r >> 1];
            __align__(16) unsigned short o[8];
            #pragma unroll
            for (int jj = 0; jj < 8; ++jj) {
                const int j = 8 * g + jj;
                const float v = (j == 0) ? ((r & 1) ? 0.f : 1.f)
                              : (j < 128 ? src[j - 1] : 0.f);
                o[jj] = f2bf(v - bf2f(f2bf(v)));
            }
            *(uint4*)&WLo[r * 136 + 8 * g] = *(const uint4*)o;
        }
        // WNT[t][r] = bf16(w^t) transposed, t in [0,257)
        for (int idx = tid; idx < 257 * 8; idx += 256) {
            const int t = idx >> 3, g = idx & 7;
            __align__(16) unsigned short o[8];
            #pragma unroll
            for (int rr = 0; rr < 8; ++rr) {
                const int r = 8 * g + rr;
                const float v = (t == 0) ? ((r & 1) ? 0.f : 1.f)
                              : ((r & 1) ? wLi[r >> 1][t - 1] : wLr[r >> 1][t - 1]);
                o[rr] = f2bf(v);
            }
            *(uint4*)&WT[t * 64 + 8 * g] = *(const uint4*)o;
        }
        if (tid < N2) {
            scratch[W256R_OFF + h * 32 + tid] = wLr[tid][255];   // w^256
            scratch[W256I_OFF + h * 32 + tid] = wLi[tid][255];
        }
    }
}

// ---------- K23: MFMA-ized Toeplitz + P + scan + state + GELU ----------------
// blockIdx remapped so the 8 batch-blocks of one h are adjacent in dispatch
// order AND congruent mod 8 (same XCD) -> per-h tables stay L2-hot.
__global__ __launch_bounds__(256, 3) void s4d_k23(
    const float* __restrict__ u,
    const float* __restrict__ Dp,
    const float* scratch,
    const unsigned short* wnhi, const unsigned short* wnlo,
    const unsigned short* wnt,
    unsigned short* y_bf)
{
    __shared__ __align__(16) unsigned short uhi[16 * 264];   // u reversed, bf16 hi
    __shared__ __align__(16) unsigned short ulo[16 * 264];   // residual
    __shared__ __align__(16) unsigned short khi[8 * 520];    // karr2 shifted copies
    __shared__ __align__(16) unsigned short klo[8 * 520];
    __shared__ __align__(16) float Plds[64 * 17];
    __shared__ __align__(16) unsigned short CkAhi[16 * 72];  // [c][2n] CkS split
    __shared__ __align__(16) unsigned short CkAlo[16 * 72];

    const int tid = threadIdx.x;
    // bijective remap: x = (h>>3)<<6 | b<<3 | (h&7)
    const int x = blockIdx.x;
    const int h = ((x >> 6) << 3) | (x & 7);
    const int b = (x >> 3) & 7;
    const int wv = tid >> 6;
    const int lane = tid & 63;
    const int l15 = lane & 15;
    const int quad = lane >> 4;

    // scan inputs hoisted to kernel top: global latency hides under A1/A2
    const int nsc = tid & 31;
    const float sc_k2r = scratch[CKR_OFF + h * 32 + nsc];
    const float sc_k2i = scratch[CKI_OFF + h * 32 + nsc];
    const float sc_wCr = scratch[W256R_OFF + h * 32 + nsc];
    const float sc_wCi = scratch[W256I_OFF + h * 32 + nsc];

    // ---- phase A1: zero karr, u->reversed splits ----
    {
        unsigned int* z1 = (unsigned int*)khi;
        unsigned int* z2 = (unsigned int*)klo;
        for (int i = tid; i < 2080; i += 256) { z1[i] = 0; z2[i] = 0; }
    }
    const float* ub = u + (size_t)(b * Hh + h) * Ll;
    #pragma unroll
    for (int q = 0; q < 4; ++q) {
        const int l = q * 1024 + tid * 4;
        const float4 v = *(const float4*)&ub[l];
        const int c = l >> 8, s = l & 255;
        const unsigned short h3 = f2bf(v.w), h2 = f2bf(v.z), h1 = f2bf(v.y), h0 = f2bf(v.x);
        // u_rev[c][252-s .. 255-s] = (u[s+3], u[s+2], u[s+1], u[s])
        uint2 dh;
        dh.x = (unsigned int)h3 | ((unsigned int)h2 << 16);
        dh.y = (unsigned int)h1 | ((unsigned int)h0 << 16);
        *(uint2*)&uhi[c * 264 + (252 - s)] = dh;
        uint2 dl;
        dl.x = (unsigned int)f2bf(v.w - bf2f(h3)) | ((unsigned int)f2bf(v.z - bf2f(h2)) << 16);
        dl.y = (unsigned int)f2bf(v.y - bf2f(h1)) | ((unsigned int)f2bf(v.x - bf2f(h0)) << 16);
        *(uint2*)&ulo[c * 264 + (252 - s)] = dl;
    }
    // own k value for later scatter
    const float kval = scratch[KG_OFF + h * CH + tid];
    const unsigned short k_hi = f2bf(kval);
    const unsigned short k_lo = f2bf(kval - bf2f(k_hi));
    __syncthreads();

    // ---- phase A2: scatter k into 8 shifted copies; P-matmul (3-product) ----
    #pragma unroll
    for (int r = 0; r < 8; ++r) {
        const int x2 = tid + 255 - r;
        khi[r * 520 + x2] = k_hi;
        klo[r * 520 + x2] = k_lo;
    }
    {   // P^T[c][2n]: wave wv owns 2n-cols [16wv, 16wv+16)
        const unsigned short* WH = wnhi + (size_t)h * (64 * 264);
        const unsigned short* WL = wnlo + (size_t)h * (64 * 136);
        f32x4 accP = {0.f, 0.f, 0.f, 0.f};
        const int wrow = 16 * wv + l15;
        #pragma unroll
        for (int j0 = 0; j0 < 256; j0 += 32) {
            const bf16x8 ah = *(const bf16x8*)&uhi[l15 * 264 + j0 + 8 * quad];
            const bf16x8 al = *(const bf16x8*)&ulo[l15 * 264 + j0 + 8 * quad];
            const bf16x8 wh = *(const bf16x8*)&WH[wrow * 264 + j0 + 8 * quad];
            accP = __builtin_amdgcn_mfma_f32_16x16x32_bf16(ah, wh, accP, 0, 0, 0);
            accP = __builtin_amdgcn_mfma_f32_16x16x32_bf16(al, wh, accP, 0, 0, 0);
            if (j0 < 128) {   // w-lo correction, same 3-product scheme as Toeplitz
                const bf16x8 wl = *(const bf16x8*)&WL[wrow * 136 + j0 + 8 * quad];
                accP = __builtin_amdgcn_mfma_f32_16x16x32_bf16(ah, wl, accP, 0, 0, 0);
            }
        }
        const int pbase = wrow * 17 + 4 * quad;
        Plds[pbase + 0] = accP[0];
        Plds[pbase + 1] = accP[1];
        Plds[pbase + 2] = accP[2];
        Plds[pbase + 3] = accP[3];
    }
    __syncthreads();

    // ---- pre-issue state-matmul B-frags from WnT (consumed after Toeplitz) ----
    bf16x8 sf[8];
    {
        const unsigned short* WT = wnt + (size_t)h * (257 * 64);
        #pragma unroll
        for (int ks2 = 0; ks2 < 2; ++ks2)
            #pragma unroll
            for (int i = 0; i < 4; ++i) {
                const int tcol = 16 * (wv + 4 * i) + l15 + 1;
                sf[ks2 * 4 + i] = *(const bf16x8*)&WT[tcol * 64 + 32 * ks2 + 8 * quad];
            }
    }

    // ---- scan (wave0 lanes 0..31) runs concurrent with Toeplitz ----
    if (tid < 32) {
        const int n = tid;
        const float k2r = sc_k2r, k2i = sc_k2i;
        const float wCr = sc_wCr, wCi = sc_wCi;
        float sr = 0.f, si = 0.f;
        #pragma unroll
        for (int c = 0; c < NCH; ++c) {
            const float vr = k2r * sr - k2i * si;       // A[c][2n]   =  Re(CkS)
            const float vi = -(k2r * si + k2i * sr);    // A[c][2n+1] = -Im(CkS)
            const unsigned short vrh = f2bf(vr), vih = f2bf(vi);
            *(unsigned int*)&CkAhi[c * 72 + 2 * n] =
                (unsigned int)vrh | ((unsigned int)vih << 16);
            *(unsigned int*)&CkAlo[c * 72 + 2 * n] =
                (unsigned int)f2bf(vr - bf2f(vrh)) |
                ((unsigned int)f2bf(vi - bf2f(vih)) << 16);
            const float pr = Plds[(2 * n) * 17 + c], pi = Plds[(2 * n + 1) * 17 + c];
            const float nr = wCr * sr - wCi * si + pr;
            si = wCr * si + wCi * sr + pi;
            sr = nr;
        }
    }

    // ---- Toeplitz: y^T[c][t] += sum_j u_rev[c][j] * karr2[t+j] ----
    f32x4 acc[4];
    #pragma unroll
    for (int i = 0; i < 4; ++i) acc[i] = (f32x4){0.f, 0.f, 0.f, 0.f};
    {
        const int r = lane & 7;
        const int roff = r * 520;
        const int half = ((lane >> 3) & 1) * 8;
        #pragma unroll
        for (int i = 0; i < 4; ++i) {
            const int nt = wv + 4 * i;
            const int jstart = (240 - 16 * nt) & ~31;
            for (int j0 = jstart; j0 < 256; j0 += 32) {
                const bf16x8 ah = *(const bf16x8*)&uhi[l15 * 264 + j0 + 8 * quad];
                const bf16x8 al = *(const bf16x8*)&ulo[l15 * 264 + j0 + 8 * quad];
                const int base = 16 * nt + j0 + 8 * quad + half;
                const bf16x8 bh = *(const bf16x8*)&khi[roff + base];
                const bf16x8 bl = *(const bf16x8*)&klo[roff + base];
                acc[i] = __builtin_amdgcn_mfma_f32_16x16x32_bf16(ah, bh, acc[i], 0, 0, 0);
                acc[i] = __builtin_amdgcn_mfma_f32_16x16x32_bf16(ah, bl, acc[i], 0, 0, 0);
                acc[i] = __builtin_amdgcn_mfma_f32_16x16x32_bf16(al, bh, acc[i], 0, 0, 0);
            }
        }
    }
    __syncthreads();

    // ---- state matmul: acc[c][t] += sum_{2n} CkA[c][2n] * Wn[2n][t+1] ----
    #pragma unroll
    for (int ks2 = 0; ks2 < 2; ++ks2) {
        const int ks = 32 * ks2;
        const bf16x8 ah = *(const bf16x8*)&CkAhi[l15 * 72 + ks + 8 * quad];
        const bf16x8 al = *(const bf16x8*)&CkAlo[l15 * 72 + ks + 8 * quad];
        #pragma unroll
        for (int i = 0; i < 4; ++i) {
            acc[i] = __builtin_amdgcn_mfma_f32_16x16x32_bf16(ah, sf[ks2 * 4 + i], acc[i], 0, 0, 0);
            acc[i] = __builtin_amdgcn_mfma_f32_16x16x32_bf16(al, sf[ks2 * 4 + i], acc[i], 0, 0, 0);
        }
    }

    // ---- epilogue: +D*u, GELU, bf16 store ----
    const float Dh = Dp[h];
    unsigned short* yo = y_bf + (size_t)(b * Hh + h) * Ll;
    #pragma unroll
    for (int i = 0; i < 4; ++i) {
        const int t = 16 * (wv + 4 * i) + l15;
        const int jrev = 255 - t;
        #pragma unroll
        for (int rr = 0; rr < 4; ++rr) {
            const int c = 4 * quad + rr;
            const float uu = bf2f(uhi[c * 264 + jrev]) + bf2f(ulo[c * 264 + jrev]);
            const float yv = acc[i][rr] + Dh * uu;
            yo[c * 256 + t] = f2bf(gelu_f(yv));
        }
    }
}

// ---------- T: y_bf (b,k,l) -> y_T (b,l,k), swizzled LDS transpose -----------
__global__ __launch_bounds__(256) void s4d_T(
    const unsigned short* y_bf, unsigned short* __restrict__ y_T)
{
    __shared__ unsigned short T[64][72];
    const int tid = threadIdx.x;
    const int b  = blockIdx.x >> 9;
    const int k0 = ((blockIdx.x >> 6) & 7) << 6;
    const int l0 = (blockIdx.x & 63) << 6;

    #pragma unroll
    for (int q = 0; q < 2; ++q) {
        const int idx = tid + 256 * q;
        const int kk = idx >> 3, lg = idx & 7;
        const uint4 v = *(const uint4*)&y_bf[((size_t)(b * Hh + k0 + kk)) * Ll + l0 + 8 * lg];
        const int gp = lg ^ ((kk >> 3) & 7);
        *(uint4*)&T[kk][8 * gp] = v;
    }
    __syncthreads();
    #pragma unroll
    for (int q = 0; q < 2; ++q) {
        const int idx = tid + 256 * q;
        const int ll = idx >> 3, kg = idx & 7;
        unsigned short o[8];
        #pragma unroll
        for (int j = 0; j < 8; ++j) {
            const int kr = 8 * kg + j;
            const int gp = (ll >> 3) ^ kg;
            o[j] = T[kr][8 * gp + (ll & 7)];
        }
        *(uint4*)&y_T[((size_t)(b * Ll + l0 + ll)) * Hh + k0 + 8 * kg] = *(uint4*)o;
    }
}

// ---------- Stage 2: 128x128 MFMA GEMM + GLU --------------------------------
// 1-D grid remapped so the 8 mt-blocks sharing a Y panel are adjacent in
// dispatch order AND congruent mod 8 (same XCD) -> Y re-reads are L2 hits.
// BOTH W and Y staged via global_load_lds + source-XOR swizzle into unpadded
// [128][64] tiles (zero staging VGPRs/VALU); inner loop is pure LDS + MFMA.
// LDS 32 KB, __launch_bounds__(256,4): accum 64 + addressing ~= 100 VGPR.
__global__ __launch_bounds__(256, 4) void s4d_s2(
    const unsigned short* __restrict__ yT,
    const unsigned short* __restrict__ Wb,
    const float* __restrict__ bias,
    float* __restrict__ out)
{
    __shared__ __align__(16) unsigned short Wlds[128 * 64];  // rows 0..63 a, 64..127 g
    __shared__ __align__(16) unsigned short Ylds[128 * 64];  // rows = l

    const int tid = threadIdx.x;
    const int x  = blockIdx.x;                 // 0..2047
    const int ctg = ((x >> 6) << 3) | (x & 7); // 0..255
    const int mt  = (x >> 3) & 7;              // 0..7
    const int b  = ctg >> 5;
    const int l0 = (ctg & 31) << 7;
    const int m0 = mt << 6;

    const int wv = tid >> 6, lane = tid & 63;
    const int l15 = lane & 15, quad = lane >> 4;

    f32x4 accA[8], accG[8];
    #pragma unroll
    for (int j = 0; j < 8; ++j) {
        accA[j] = (f32x4){0.f, 0.f, 0.f, 0.f};
        accG[j] = (f32x4){0.f, 0.f, 0.f, 0.f};
    }

    for (int kk = 0; kk < Hh; kk += 64) {
        #pragma unroll
        for (int q = 0; q < 4; ++q) {
            const int idx = tid + 256 * q;
            const int rr = idx >> 3, kg = idx & 7;
            const int sw = kg ^ (rr & 7);              // source chunk permutation
            const int grow = m0 + rr + ((rr >> 6) * 448);
            gl2lds16(&Wb[grow * Hh + kk + 8 * sw], &Wlds[8 * idx]);
            gl2lds16(&yT[((size_t)(b * Ll + l0 + rr)) * Hh + kk + 8 * sw], &Ylds[8 * idx]);
        }
        __syncthreads();

        #pragma unroll
        for (int ks = 0; ks < 64; ks += 32) {
            const int c0 = (ks >> 3) + quad;
            const int arow = 16 * wv + l15;
            const bf16x8 af = *(const bf16x8*)&Wlds[arow * 64 + 8 * (c0 ^ (arow & 7))];
            const int grow2 = 64 + arow;
            const bf16x8 gf = *(const bf16x8*)&Wlds[grow2 * 64 + 8 * (c0 ^ (grow2 & 7))];
            #pragma unroll
            for (int j = 0; j < 8; ++j) {
                const int brow = 16 * j + l15;
                const bf16x8 bfr = *(const bf16x8*)&Ylds[brow * 64 + 8 * (c0 ^ (brow & 7))];
                accA[j] = __builtin_amdgcn_mfma_f32_16x16x32_bf16(af, bfr, accA[j], 0, 0, 0);
                accG[j] = __builtin_amdgcn_mfma_f32_16x16x32_bf16(gf, bfr, accG[j], 0, 0, 0);
            }
        }
        __syncthreads();
    }

    const int mb = m0 + 16 * wv + 4 * quad;
    float bA[4], bG[4];
    #pragma unroll
    for (int rr = 0; rr < 4; ++rr) { bA[rr] = bias[mb + rr]; bG[rr] = bias[mb + rr + 512]; }

    #pragma unroll
    for (int j = 0; j < 8; ++j) {
        const int l = l0 + 16 * j + l15;
        #pragma unroll
        for (int rr = 0; rr < 4; ++rr) {
            const float a = accA[j][rr] + bA[rr];
            const float g = accG[j][rr] + bG[rr];
            out[((size_t)(b * Hh + mb + rr)) * Ll + l] = a / (1.f + expf(-g));
        }
    }
}

extern "C" void kernel_launch(void* const* d_in, const int* in_sizes, int n_in,
                              void* d_out, int out_size, void* d_ws, size_t ws_size,
                              hipStream_t stream)
{
    const float* u          = (const float*)d_in[0];
    const float* log_dt     = (const float*)d_in[1];
    const float* C_re       = (const float*)d_in[2];
    const float* C_im       = (const float*)d_in[3];
    const float* log_A_real = (const float*)d_in[4];
    const float* A_imag     = (const float*)d_in[5];
    const float* Dp         = (const float*)d_in[6];
    const float* W          = (const float*)d_in[7];
    const float* bias       = (const float*)d_in[8];

    float* out = (float*)d_out;
    float* scratch = (float*)d_out;                         // floats [32Mi, ...)
    unsigned short* y_bf = (unsigned short*)d_out;          // bf16 [0, 32MiB)
    unsigned short* wnhi = (unsigned short*)d_out + WNHI_OFF;  // 16.5 MiB @ 36 MiB
    unsigned short* wnlo = (unsigned short*)d_out + WNLO_OFF;  // 8.5 MiB @ 52.5 MiB
    unsigned short* y_T  = (unsigned short*)d_ws;           // 32 MiB
    unsigned short* wnt  = (unsigned short*)d_ws;           // 16.1 MiB, freed before s4d_T writes y_T
    unsigned short* Wb   = (unsigned short*)((char*)d_ws + (32u << 20)); // 1 MiB

    s4d_k1<<<dim3(Hh), dim3(256), 0, stream>>>(
        log_dt, C_re, C_im, log_A_real, A_imag, W, scratch, Wb, wnhi, wnlo, wnt);
    s4d_k23<<<dim3(Bb * Hh), dim3(256), 0, stream>>>(
        u, Dp, scratch, wnhi, wnlo, wnt, y_bf);
    s4d_T<<<dim3(Bb * Hh), dim3(256), 0, stream>>>(y_bf, y_T);
    s4d_s2<<<dim3(2048), dim3(256), 0, stream>>>(y_T, Wb, bias, out);
}